// Round 4
// baseline (212.325 us; speedup 1.0000x reference)
//
#include <hip/hip_runtime.h>
#include <math.h>

// Problem constants (fixed by setup_inputs)
#define CIN      8
#define H_IN     100
#define W_IN     136
#define NPIX     (H_IN * W_IN)       // 13600
#define OH       (2 * H_IN)          // 200
#define OW       (2 * W_IN)          // 272
#define ONPIX    (OH * OW)           // 54400
#define NPARAMS  169
#define EPSV     1e-5f
#define NSLICE   4                   // row-slices per instance (25 rows each, NO overlap)
#define KG4      34                  // 136/4 col-groups of 4 src px
#define TASKS_A  (25 * KG4)          // 850 phase-A tasks per slice
#define KGROUPS  34                  // 272/8 output col-groups
#define TASKS_B  (25 * KGROUPS)      // 850 dice tasks per quarter

// param layout: w0[8][10] @0, w1[8][8] @80, w2[8] @144, b0 @152, b1 @160, b2 @168

__device__ __forceinline__ float sigmoidf_fast(float x) {
    float e = __expf(-x);
    return __builtin_amdgcn_rcpf(1.f + e);
}

// R2/R3 lessons: occupancy bump neutral, intra-block load pipelining negative.
// The fused kernel's real cost was PHASE SERIALIZATION: compute-only phase A
// (HBM idle) -> barrier -> BW-burst phase B (VALU idle), synchronized across
// all co-resident blocks. Split kernels instead: logits_kernel is pure
// compute (no LDS tile, no barrier, no overlap rows); dice_kernel is pure
// streaming that reads gt at full HBM rate from its first instruction.
// Math and task->thread mapping are IDENTICAL to the fused version =>
// bit-identical partials (absmax stays 0).

__global__ __launch_bounds__(256, 4)
void logits_kernel(const float* __restrict__ mask_feats,   // [N,8,100,136]
                   const float* __restrict__ params,       // [n,169]
                   const float* __restrict__ locs,         // [n,2]
                   const int*   __restrict__ im_inds,      // [n]
                   const int*   __restrict__ fpn_levels,   // [n]
                   float*       __restrict__ logits)       // [n,13600]
{
    const int inst  = blockIdx.x >> 2;
    const int slice = blockIdx.x & 3;
    const int tid   = threadIdx.x;
    const int r_start = 25 * slice;            // exact 25-row slice, no overlap

    // Block-uniform weight pointer -> scalar K$ loads, zero VALU/LDS cost.
    const float* __restrict__ wp = params + (size_t)inst * NPARAMS;

    const int   im  = im_inds[inst];
    const int   lvl = fpn_levels[inst];
    const float inv_soi = exp2f(-(float)(3 + lvl));  // SOI = 8*2^lvl, exact
    const float lx = locs[inst * 2 + 0];
    const float ly = locs[inst * 2 + 1];
    const float dx8 = 8.f * inv_soi;

    const float* feat = mask_feats + (size_t)im * (CIN * NPIX);
    const int goff = r_start * W_IN;
    float* lg = logits + (size_t)inst * NPIX + goff;

    // Task = 4 consecutive px in one row. All 8 channel float4s issued upfront
    // (32 dedicated regs), then the 4 px processed SERIALLY with layers 1+2
    // fused per output channel (peak ~58 VGPR). Invalid tail tasks skipped.
    #pragma unroll 1
    for (int it = 0; it < 4; ++it) {
        const int t = it * 256 + tid;
        if (t < TASKS_A) {
            const int r  = t / KG4;                    // local row 0..24
            const int k  = t - r * KG4;                // col-group
            const int lpx = r * W_IN + 4 * k;
            const float* fb = feat + (goff + lpx);

            // all 8 channel loads in flight together
            float4 f[8];
            #pragma unroll
            for (int c = 0; c < CIN; ++c)
                f[c] = *(const float4*)(fb + c * NPIX);

            float in0[4];
            in0[0] = (lx - (float)(32 * k + 4)) * inv_soi;
            in0[1] = in0[0] - dx8;
            in0[2] = in0[1] - dx8;
            in0[3] = in0[2] - dx8;
            const float in1 = (ly - (float)((r_start + r) * 8 + 4)) * inv_soi;

            float o4[4];

#define DO_PX(J, COMP)                                                        \
            {                                                                 \
                float aj[8];                                                  \
                _Pragma("unroll")                                             \
                for (int o = 0; o < 8; ++o)                                   \
                    aj[o] = fmaf(wp[o * 10], in0[J],                          \
                                 fmaf(wp[o * 10 + 1], in1, wp[152 + o]));     \
                _Pragma("unroll")                                             \
                for (int c = 0; c < 8; ++c) {                                 \
                    _Pragma("unroll")                                         \
                    for (int o = 0; o < 8; ++o)                               \
                        aj[o] = fmaf(wp[o * 10 + 2 + c], f[c].COMP, aj[o]);   \
                }                                                             \
                _Pragma("unroll")                                             \
                for (int o = 0; o < 8; ++o)                                   \
                    aj[o] = fmaxf(aj[o], 0.f);                                \
                float acc = wp[168];                                          \
                _Pragma("unroll")                                             \
                for (int o = 0; o < 8; ++o) {                                 \
                    float tt = wp[160 + o];                                   \
                    _Pragma("unroll")                                         \
                    for (int i = 0; i < 8; ++i)                               \
                        tt = fmaf(wp[80 + o * 8 + i], aj[i], tt);             \
                    acc = fmaf(wp[144 + o], fmaxf(tt, 0.f), acc);             \
                }                                                             \
                o4[J] = acc;                                                  \
            }

            DO_PX(0, x)
            DO_PX(1, y)
            DO_PX(2, z)
            DO_PX(3, w)
#undef DO_PX

            float4 ov = {o4[0], o4[1], o4[2], o4[3]};
            *(float4*)(lg + lpx) = ov;   // coalesced 16B store
        }
    }
}

// Pure streaming kernel: gt (108.8 MB, HBM after the harness fills flush L3)
// streams from the first instruction; logits (27.2 MB) hit L3 (just written).
// ~2000 blocks x 4 waves ~= full occupancy; TLP hides latency (no pipelining
// needed per R3 lesson / T14-null regime).
__global__ __launch_bounds__(256, 5)
void dice_kernel(const float* __restrict__ logits,    // [n,13600]
                 const float* __restrict__ gt,        // [n,1,200,272]
                 float*       __restrict__ partials)  // [n*4][3]
{
    const int inst = blockIdx.x >> 2;
    const int q    = blockIdx.x & 3;
    const int tid  = threadIdx.x;
    const int pair_base = 25 * q;

    __shared__ float s_red[12];

    const float* lgp = logits + (size_t)inst * NPIX;
    const float* gtp = gt + (size_t)inst * ONPIX;

    float inter = 0.f, ssum = 0.f, tsum = 0.f;

    // Output row 2p   = avg(src row p-1, src row p)   (p=0: src row 0)
    // Output row 2p+1 = src row p
    // Output cols: o[2j]=avg adjacent src cols, o[2j+1]=src col (left clamp)
    #pragma unroll 1
    for (int base = 0; base < TASKS_B; base += 256) {
        const int task = base + tid;
        if (task < TASKS_B) {
            const int pl = task / KGROUPS;
            const int k  = task - pl * KGROUPS;
            const int pg = pair_base + pl;
            const float* E = lgp + (size_t)pg * W_IN;
            const float* P = lgp + (size_t)(pg > 0 ? pg - 1 : 0) * W_IN;
            const int c0  = 4 * k;
            const int cm1 = (k > 0) ? c0 - 1 : 0;

            // issue all loads upfront (gt first: longest latency)
            const float* g0 = gtp + (size_t)(2 * pg) * OW + 8 * k;
            const float4 ga = *(const float4*)(g0);            // avg row, cols 0-3
            const float4 gb = *(const float4*)(g0 + 4);        // avg row, cols 4-7
            const float4 gc = *(const float4*)(g0 + OW);       // exact row, cols 0-3
            const float4 gd = *(const float4*)(g0 + OW + 4);   // exact row, cols 4-7
            const float4 e4 = *(const float4*)(E + c0);
            const float  em = E[cm1];
            const float4 p4 = *(const float4*)(P + c0);
            const float  pm = P[cm1];

            const float ecur[4] = {e4.x, e4.y, e4.z, e4.w};
            const float pcur[4] = {p4.x, p4.y, p4.z, p4.w};
            const float gav[8] = {ga.x, ga.y, ga.z, ga.w, gb.x, gb.y, gb.z, gb.w};
            const float gex[8] = {gc.x, gc.y, gc.z, gc.w, gd.x, gd.y, gd.z, gd.w};

            float Se_prev = em;
            float Sa_prev = 0.5f * (em + pm);
            #pragma unroll
            for (int j = 0; j < 4; ++j) {
                const float Se = ecur[j];
                const float Sa = 0.5f * (ecur[j] + pcur[j]);
                {
                    float s = sigmoidf_fast(0.5f * (Sa_prev + Sa));
                    float t2 = gav[2 * j];
                    inter = fmaf(s, t2, inter); ssum = fmaf(s, s, ssum); tsum = fmaf(t2, t2, tsum);
                    s = sigmoidf_fast(Sa);
                    t2 = gav[2 * j + 1];
                    inter = fmaf(s, t2, inter); ssum = fmaf(s, s, ssum); tsum = fmaf(t2, t2, tsum);
                }
                {
                    float s = sigmoidf_fast(0.5f * (Se_prev + Se));
                    float t2 = gex[2 * j];
                    inter = fmaf(s, t2, inter); ssum = fmaf(s, s, ssum); tsum = fmaf(t2, t2, tsum);
                    s = sigmoidf_fast(Se);
                    t2 = gex[2 * j + 1];
                    inter = fmaf(s, t2, inter); ssum = fmaf(s, s, ssum); tsum = fmaf(t2, t2, tsum);
                }
                Se_prev = Se;
                Sa_prev = Sa;
            }
        }
    }

    // block reduction (4 waves of 64)
    #pragma unroll
    for (int off = 32; off > 0; off >>= 1) {
        inter += __shfl_down(inter, off, 64);
        ssum  += __shfl_down(ssum,  off, 64);
        tsum  += __shfl_down(tsum,  off, 64);
    }
    const int wid = tid >> 6;
    if ((tid & 63) == 0) {
        s_red[wid * 3 + 0] = inter;
        s_red[wid * 3 + 1] = ssum;
        s_red[wid * 3 + 2] = tsum;
    }
    __syncthreads();
    if (tid == 0) {
        float I = 0.f, S = 0.f, T = 0.f;
        #pragma unroll
        for (int w = 0; w < 4; ++w) {
            I += s_red[w * 3 + 0];
            S += s_red[w * 3 + 1];
            T += s_red[w * 3 + 2];
        }
        partials[blockIdx.x * 3 + 0] = I;
        partials[blockIdx.x * 3 + 1] = S;
        partials[blockIdx.x * 3 + 2] = T;
    }
}

__global__ __launch_bounds__(512)
void loss_mean_kernel(const float* __restrict__ partials, float* __restrict__ out, int n)
{
    __shared__ float s_red[8];
    float v = 0.f;
    for (int i = threadIdx.x; i < n; i += 512) {
        float I = 0.f, S = 0.f, T = 0.f;
        #pragma unroll
        for (int s = 0; s < NSLICE; ++s) {
            const float* p = partials + (size_t)(i * NSLICE + s) * 3;
            I += p[0];
            S += p[1];
            T += p[2];
        }
        v += 1.f - 2.f * I / (S + T + EPSV);
    }
    #pragma unroll
    for (int off = 32; off > 0; off >>= 1) v += __shfl_down(v, off, 64);
    const int wid = threadIdx.x >> 6;
    if ((threadIdx.x & 63) == 0) s_red[wid] = v;
    __syncthreads();
    if (threadIdx.x == 0) {
        float s = 0.f;
        #pragma unroll
        for (int w = 0; w < 8; ++w) s += s_red[w];
        out[0] = s / (float)n;
    }
}

extern "C" void kernel_launch(void* const* d_in, const int* in_sizes, int n_in,
                              void* d_out, int out_size, void* d_ws, size_t ws_size,
                              hipStream_t stream)
{
    const float* mask_feats = (const float*)d_in[0];
    const float* params     = (const float*)d_in[1];
    const float* locs       = (const float*)d_in[2];
    const float* gt         = (const float*)d_in[3];
    const int*   im_inds    = (const int*)d_in[4];
    const int*   fpn_levels = (const int*)d_in[5];
    // d_in[6] = mask_feat_stride (always 8 for this problem)

    const int n = in_sizes[4];          // 500 instances

    // workspace layout: partials [n*4*3 floats] @0, logits [n*13600 floats] @32KB
    float* partials = (float*)d_ws;
    float* logits   = (float*)((char*)d_ws + (32 << 10));

    logits_kernel<<<n * NSLICE, 256, 0, stream>>>(mask_feats, params, locs,
                                                  im_inds, fpn_levels, logits);
    dice_kernel<<<n * NSLICE, 256, 0, stream>>>(logits, gt, partials);
    loss_mean_kernel<<<1, 512, 0, stream>>>(partials, (float*)d_out, n);
}

// Round 5
// 179.759 us; speedup vs baseline: 1.1812x; 1.1812x over previous
//
#include <hip/hip_runtime.h>
#include <math.h>

// Problem constants (fixed by setup_inputs)
#define CIN      8
#define H_IN     100
#define W_IN     136
#define NPIX     (H_IN * W_IN)       // 13600
#define OH       (2 * H_IN)          // 200
#define OW       (2 * W_IN)          // 272
#define ONPIX    (OH * OW)           // 54400
#define NPARAMS  169
#define EPSV     1e-5f
#define NSLICE   4                   // row-slices per instance
#define KG4      34                  // 136/4 col-groups of 4 src px
#define KGROUPS  34                  // 272/8 output col-groups
#define TASKS_B  (25 * KGROUPS)      // 850 phase-B tasks per slice

// param layout: w0[8][10] @0, w1[8][8] @80, w2[8] @144, b0 @152, b1 @160, b2 @168

__device__ __forceinline__ float sigmoidf_fast(float x) {
    float e = __expf(-x);
    return __builtin_amdgcn_rcpf(1.f + e);
}

// Session ledger:
//  R1: gt->LDS prefetch          -> +11us (vmcnt in-order drain stalls phase A)
//  R2: (256,5) occupancy bump    -> neutral (stall is synchronous across waves)
//  R3: 2-px reg ping-pong        -> +4us (task overhead > latency hidden)
//  R4: kernel split A/B          -> +30us (block stagger already overlaps the
//      phases device-wide; a dispatch boundary serializes them + 54MB traffic)
// Standing theory: phase A is throttled by REPEATED SCALAR WEIGHT TRAFFIC —
// ~160 weight words re-walked PER PIXEL (169 floats can't fit in SGPRs), each
// use-group carrying an lgkm wait. Fix here: walk the weights once per TWO
// pixels (DO_PAIR), halving s_load traffic and doubling independent FMA
// chains per wait. Per-pixel FMA order unchanged => bit-identical output.
// VGPR ~58 -> (256,4) fit; (256,5) would now spill.
__global__ __launch_bounds__(256, 4)
void mask_head_fused(const float* __restrict__ mask_feats,   // [N,8,100,136]
                     const float* __restrict__ params,       // [n,169]
                     const float* __restrict__ locs,         // [n,2]
                     const float* __restrict__ gt,           // [n,1,200,272]
                     const int*   __restrict__ im_inds,      // [n]
                     const int*   __restrict__ fpn_levels,   // [n]
                     float*       __restrict__ partials)     // [n*4][3]
{
    const int inst  = blockIdx.x >> 2;
    const int slice = blockIdx.x & 3;
    const int tid   = threadIdx.x;

    // src rows for this slice: max(25*slice-1,0) .. 25*slice+24
    const int r_start = (slice == 0) ? 0 : 25 * slice - 1;
    const int nrows   = (slice == 0) ? 25 : 26;
    const int ntask   = nrows * KG4;               // 850 or 884

    __shared__ float s_logit[26 * W_IN];           // 14144 B
    __shared__ float s_red[12];

    // Block-uniform weight pointer -> scalar K$ loads.
    const float* __restrict__ wp = params + (size_t)inst * NPARAMS;

    const int   im  = im_inds[inst];
    const int   lvl = fpn_levels[inst];
    const float inv_soi = exp2f(-(float)(3 + lvl));  // SOI = 8*2^lvl, exact
    const float lx = locs[inst * 2 + 0];
    const float ly = locs[inst * 2 + 1];
    const float dx8 = 8.f * inv_soi;

    const float* feat = mask_feats + (size_t)im * (CIN * NPIX);
    const int goff = r_start * W_IN;   // global pixel offset of local row 0

    // ---------------- Phase A: logits -> LDS ----------------
    // Task = 4 consecutive px in one row. All 8 channel float4s issued upfront
    // (32 dedicated regs), then px processed in PAIRS inside the weight walk:
    // each scalar weight fetched once per 2 px (was once per px).
    #pragma unroll 1
    for (int it = 0; it < 4; ++it) {
        const int t = it * 256 + tid;
        if (t < ntask) {
            const int r  = t / KG4;                    // local row
            const int k  = t - r * KG4;                // col-group
            const int lpx = r * W_IN + 4 * k;
            const float* fb = feat + (goff + lpx);

            // all 8 channel loads in flight together
            float4 f[8];
            #pragma unroll
            for (int c = 0; c < CIN; ++c)
                f[c] = *(const float4*)(fb + c * NPIX);

            float in0[4];
            in0[0] = (lx - (float)(32 * k + 4)) * inv_soi;
            in0[1] = in0[0] - dx8;
            in0[2] = in0[1] - dx8;
            in0[3] = in0[2] - dx8;
            const float in1 = (ly - (float)((r_start + r) * 8 + 4)) * inv_soi;

            float o4[4];

            // Per-px FMA order identical to the per-px macro (bit-identical
            // results); only interleaved between the two px of a pair.
#define DO_PAIR(J0, J1, CX, CY)                                               \
            {                                                                 \
                float a0[8], a1[8];                                           \
                _Pragma("unroll")                                             \
                for (int o = 0; o < 8; ++o) {                                 \
                    const float b = fmaf(wp[o * 10 + 1], in1, wp[152 + o]);   \
                    a0[o] = fmaf(wp[o * 10], in0[J0], b);                     \
                    a1[o] = fmaf(wp[o * 10], in0[J1], b);                     \
                }                                                             \
                _Pragma("unroll")                                             \
                for (int c = 0; c < 8; ++c) {                                 \
                    _Pragma("unroll")                                         \
                    for (int o = 0; o < 8; ++o) {                             \
                        const float w = wp[o * 10 + 2 + c];                   \
                        a0[o] = fmaf(w, f[c].CX, a0[o]);                      \
                        a1[o] = fmaf(w, f[c].CY, a1[o]);                      \
                    }                                                         \
                }                                                             \
                _Pragma("unroll")                                             \
                for (int o = 0; o < 8; ++o) {                                 \
                    a0[o] = fmaxf(a0[o], 0.f);                                \
                    a1[o] = fmaxf(a1[o], 0.f);                                \
                }                                                             \
                float acc0 = wp[168], acc1 = wp[168];                         \
                _Pragma("unroll")                                             \
                for (int o = 0; o < 8; ++o) {                                 \
                    float t0 = wp[160 + o], t1 = wp[160 + o];                 \
                    _Pragma("unroll")                                         \
                    for (int i = 0; i < 8; ++i) {                             \
                        const float w = wp[80 + o * 8 + i];                   \
                        t0 = fmaf(w, a0[i], t0);                              \
                        t1 = fmaf(w, a1[i], t1);                              \
                    }                                                         \
                    acc0 = fmaf(wp[144 + o], fmaxf(t0, 0.f), acc0);          \
                    acc1 = fmaf(wp[144 + o], fmaxf(t1, 0.f), acc1);          \
                }                                                             \
                o4[J0] = acc0;                                                \
                o4[J1] = acc1;                                                \
            }

            DO_PAIR(0, 1, x, y)
            DO_PAIR(2, 3, z, w)
#undef DO_PAIR

            float4 ov = {o4[0], o4[1], o4[2], o4[3]};
            *(float4*)(s_logit + lpx) = ov;   // 16B-aligned
        }
    }

    __syncthreads();

    // ---------------- Phase B: structured x2 upsample + sigmoid + dice ----------
    // Output row 2p   = avg(src row p-1, src row p)   (p=0: src row 0)
    // Output row 2p+1 = src row p
    // Output cols: o[2j]=avg of adjacent src cols, o[2j+1]=src col (left edge clamp)
    float inter = 0.f, ssum = 0.f, tsum = 0.f;
    const float* gtp = gt + (size_t)inst * ONPIX;
    const int pair_base = 25 * slice;

    #pragma unroll 1
    for (int base = 0; base < TASKS_B; base += 256) {
        const int task = base + tid;
        if (task < TASKS_B) {
            const int pl = task / KGROUPS;
            const int k  = task - pl * KGROUPS;
            const int pg = pair_base + pl;
            const int er = pg - r_start;                       // exact src row (local)
            const int pr = (pg > 0 ? pg - 1 : 0) - r_start;    // prev src row (local)
            const float* E = s_logit + er * W_IN;
            const float* P = s_logit + pr * W_IN;
            const int c0  = 4 * k;
            const int cm1 = (k > 0) ? c0 - 1 : 0;

            // issue all loads upfront (gt first: longest latency)
            const float* g0 = gtp + (size_t)(2 * pg) * OW + 8 * k;
            const float4 ga = *(const float4*)(g0);            // avg row, cols 0-3
            const float4 gb = *(const float4*)(g0 + 4);        // avg row, cols 4-7
            const float4 gc = *(const float4*)(g0 + OW);       // exact row, cols 0-3
            const float4 gd = *(const float4*)(g0 + OW + 4);   // exact row, cols 4-7
            const float4 e4 = *(const float4*)(E + c0);
            const float  em = E[cm1];
            const float4 p4 = *(const float4*)(P + c0);
            const float  pm = P[cm1];

            const float ecur[4] = {e4.x, e4.y, e4.z, e4.w};
            const float pcur[4] = {p4.x, p4.y, p4.z, p4.w};
            const float gav[8] = {ga.x, ga.y, ga.z, ga.w, gb.x, gb.y, gb.z, gb.w};
            const float gex[8] = {gc.x, gc.y, gc.z, gc.w, gd.x, gd.y, gd.z, gd.w};

            float Se_prev = em;
            float Sa_prev = 0.5f * (em + pm);
            #pragma unroll
            for (int j = 0; j < 4; ++j) {
                const float Se = ecur[j];
                const float Sa = 0.5f * (ecur[j] + pcur[j]);
                {
                    float s = sigmoidf_fast(0.5f * (Sa_prev + Sa));
                    float t2 = gav[2 * j];
                    inter = fmaf(s, t2, inter); ssum = fmaf(s, s, ssum); tsum = fmaf(t2, t2, tsum);
                    s = sigmoidf_fast(Sa);
                    t2 = gav[2 * j + 1];
                    inter = fmaf(s, t2, inter); ssum = fmaf(s, s, ssum); tsum = fmaf(t2, t2, tsum);
                }
                {
                    float s = sigmoidf_fast(0.5f * (Se_prev + Se));
                    float t2 = gex[2 * j];
                    inter = fmaf(s, t2, inter); ssum = fmaf(s, s, ssum); tsum = fmaf(t2, t2, tsum);
                    s = sigmoidf_fast(Se);
                    t2 = gex[2 * j + 1];
                    inter = fmaf(s, t2, inter); ssum = fmaf(s, s, ssum); tsum = fmaf(t2, t2, tsum);
                }
                Se_prev = Se;
                Sa_prev = Sa;
            }
        }
    }

    // block reduction (4 waves of 64)
    #pragma unroll
    for (int off = 32; off > 0; off >>= 1) {
        inter += __shfl_down(inter, off, 64);
        ssum  += __shfl_down(ssum,  off, 64);
        tsum  += __shfl_down(tsum,  off, 64);
    }
    const int wid = tid >> 6;
    if ((tid & 63) == 0) {
        s_red[wid * 3 + 0] = inter;
        s_red[wid * 3 + 1] = ssum;
        s_red[wid * 3 + 2] = tsum;
    }
    __syncthreads();
    if (tid == 0) {
        float I = 0.f, S = 0.f, T = 0.f;
        #pragma unroll
        for (int w = 0; w < 4; ++w) {
            I += s_red[w * 3 + 0];
            S += s_red[w * 3 + 1];
            T += s_red[w * 3 + 2];
        }
        partials[blockIdx.x * 3 + 0] = I;
        partials[blockIdx.x * 3 + 1] = S;
        partials[blockIdx.x * 3 + 2] = T;
    }
}

__global__ __launch_bounds__(512)
void loss_mean_kernel(const float* __restrict__ partials, float* __restrict__ out, int n)
{
    __shared__ float s_red[8];
    float v = 0.f;
    for (int i = threadIdx.x; i < n; i += 512) {
        float I = 0.f, S = 0.f, T = 0.f;
        #pragma unroll
        for (int s = 0; s < NSLICE; ++s) {
            const float* p = partials + (size_t)(i * NSLICE + s) * 3;
            I += p[0];
            S += p[1];
            T += p[2];
        }
        v += 1.f - 2.f * I / (S + T + EPSV);
    }
    #pragma unroll
    for (int off = 32; off > 0; off >>= 1) v += __shfl_down(v, off, 64);
    const int wid = threadIdx.x >> 6;
    if ((threadIdx.x & 63) == 0) s_red[wid] = v;
    __syncthreads();
    if (threadIdx.x == 0) {
        float s = 0.f;
        #pragma unroll
        for (int w = 0; w < 8; ++w) s += s_red[w];
        out[0] = s / (float)n;
    }
}

extern "C" void kernel_launch(void* const* d_in, const int* in_sizes, int n_in,
                              void* d_out, int out_size, void* d_ws, size_t ws_size,
                              hipStream_t stream)
{
    const float* mask_feats = (const float*)d_in[0];
    const float* params     = (const float*)d_in[1];
    const float* locs       = (const float*)d_in[2];
    const float* gt         = (const float*)d_in[3];
    const int*   im_inds    = (const int*)d_in[4];
    const int*   fpn_levels = (const int*)d_in[5];
    // d_in[6] = mask_feat_stride (always 8 for this problem)

    const int n = in_sizes[4];          // 500 instances
    float* partials = (float*)d_ws;     // n*NSLICE*3 floats

    mask_head_fused<<<n * NSLICE, 256, 0, stream>>>(mask_feats, params, locs, gt,
                                                    im_inds, fpn_levels, partials);
    loss_mean_kernel<<<1, 512, 0, stream>>>(partials, (float*)d_out, n);
}